// Round 10
// baseline (355.959 us; speedup 1.0000x reference)
//
#include <hip/hip_runtime.h>
#include <math.h>

typedef __bf16 bf16;
typedef __bf16 bf16x8 __attribute__((ext_vector_type(8)));
typedef __bf16 bf16x4 __attribute__((ext_vector_type(4)));
typedef float f32x4 __attribute__((ext_vector_type(4)));

#define DEV static __device__ __forceinline__
#define AS1 __attribute__((address_space(1)))
#define AS3 __attribute__((address_space(3)))

constexpr int kBatch = 4, kSeq = 2048, kDModel = 1024;
constexpr int kDInner = 2048, kHeads = 32;
constexpr int kConvDim = 2176, kDInProj = 4256, kNPad1 = 4352;
constexpr int kRows = kBatch * kSeq; // 8192
constexpr int kChunk = 64, kNChunk = kSeq / kChunk; // 32
constexpr float kRmsEps = 1.1920929e-07f;
constexpr float kGnEps = 1e-5f;
constexpr int kW1Blocks = kNPad1 * kDModel / 256;   // 17408
constexpr int kW2Blocks = kDModel * kDInner / 1024; // 2048

DEV float siluf(float x) { return x / (1.f + expf(-x)); }

DEV float block_reduce_sum(float v, float* red, int tid) {
#pragma unroll
  for (int m = 1; m < 64; m <<= 1) v += __shfl_xor(v, m);
  if ((tid & 63) == 0) red[tid >> 6] = v;
  __syncthreads();
  return red[0] + red[1] + red[2] + red[3];
}

// ------ fused prologue: RMSNorm (+row scale) | w1 cast+pad | w2*gw cast ------
__global__ __launch_bounds__(256) void k_pre(
    const float* __restrict__ x, const float* __restrict__ nw,
    bf16* __restrict__ xnb, float* __restrict__ rs,
    const float* __restrict__ w1, bf16* __restrict__ w1b,
    const float* __restrict__ w2, const float* __restrict__ gw,
    bf16* __restrict__ w2b) {
  const int blk = blockIdx.x;
  const int tid = threadIdx.x;
  if (blk < kRows) { // RMSNorm row
    const int row = blk;
    float4 v = ((const float4*)(x + (size_t)row * kDModel))[tid];
    __shared__ float red[4];
    float ss = block_reduce_sum(v.x * v.x + v.y * v.y + v.z * v.z + v.w * v.w, red, tid);
    float scale = rsqrtf(ss * (1.f / kDModel) + kRmsEps);
    if (tid == 0) rs[row] = scale;
    float4 wv = ((const float4*)nw)[tid];
    bf16x4 ov;
    ov[0] = (bf16)(v.x * scale * wv.x);
    ov[1] = (bf16)(v.y * scale * wv.y);
    ov[2] = (bf16)(v.z * scale * wv.z);
    ov[3] = (bf16)(v.w * scale * wv.w);
    *(bf16x4*)(xnb + (size_t)row * kDModel + tid * 4) = ov;
  } else if (blk < kRows + kW1Blocks) { // w1 cast + zero-pad rows >= 4256
    const size_t idx = (size_t)(blk - kRows) * 256 + tid;
    const int row = (int)(idx >> 10);
    w1b[idx] = (bf16)(row < kDInProj ? w1[idx] : 0.f);
  } else { // w2b[n,k] = w2[n,k] * gw[k]
    const size_t i4 = (size_t)(blk - kRows - kW1Blocks) * 256 + tid;
    const int k4 = (int)((i4 * 4) & (kDInner - 1));
    float4 v = ((const float4*)w2)[i4];
    float4 g = *(const float4*)(gw + k4);
    bf16x4 o;
    o[0] = (bf16)(v.x * g.x); o[1] = (bf16)(v.y * g.y);
    o[2] = (bf16)(v.z * g.z); o[3] = (bf16)(v.w * g.w);
    ((bf16x4*)w2b)[i4] = o;
  }
}

// ---------------- mean pool over S (deterministic 2-stage) ----------------
__global__ __launch_bounds__(128) void k_pool1(const bf16* __restrict__ xnb,
                                               float* __restrict__ part) {
  const int g = blockIdx.x, b = blockIdx.y;
  const int tid = threadIdx.x;
  const bf16* base = xnb + ((size_t)b * kSeq + (size_t)g * 32) * kDModel + tid * 8;
  float acc[8] = {0, 0, 0, 0, 0, 0, 0, 0};
  for (int r = 0; r < 32; ++r) {
    bf16x8 v = *(const bf16x8*)(base + (size_t)r * kDModel);
#pragma unroll
    for (int j = 0; j < 8; ++j) acc[j] += (float)v[j];
  }
  float* o = part + ((size_t)b * 64 + g) * kDModel + tid * 8;
#pragma unroll
  for (int j = 0; j < 8; ++j) o[j] = acc[j];
}

__global__ __launch_bounds__(256) void k_pool2(const float* __restrict__ part,
                                               float* __restrict__ mean) {
  const int idx = blockIdx.x * 256 + threadIdx.x; // 4096
  const int b = idx >> 10, d = idx & 1023;
  float s = 0.f;
  for (int g = 0; g < 64; ++g) s += part[((size_t)b * 64 + g) * kDModel + d];
  mean[idx] = s * (1.f / kSeq);
}

// ---------------- router MLP + softmax ----------------
__global__ __launch_bounds__(128) void k_router(const float* __restrict__ mean,
                                                const float* __restrict__ w1,
                                                const float* __restrict__ b1,
                                                const float* __restrict__ w2,
                                                const float* __restrict__ b2,
                                                float* __restrict__ pfm) {
  __shared__ float hbuf[4][32];
  __shared__ float logit[4][3];
  const int t = threadIdx.x;
  {
    int b = t >> 5, j = t & 31;
    float s = b1[j];
    for (int d = 0; d < kDModel; ++d) s += mean[b * kDModel + d] * w1[j * kDModel + d];
    hbuf[b][j] = siluf(s);
  }
  __syncthreads();
  if (t < 12) {
    int b = t / 3, k = t % 3;
    float s = b2[k];
    for (int j = 0; j < 32; ++j) s += hbuf[b][j] * w2[k * 32 + j];
    logit[b][k] = s;
  }
  __syncthreads();
  if (t < 4) {
    float m = fmaxf(logit[t][0], fmaxf(logit[t][1], logit[t][2]));
    float e0 = expf(logit[t][0] - m), e1 = expf(logit[t][1] - m), e2 = expf(logit[t][2] - m);
    float inv = 1.f / (e0 + e1 + e2);
    pfm[t] = e0 * inv;            // p_fast[b]
    pfm[4 + t] = (e1 + e2) * inv; // p_mamba[b]
  }
}

// ====== GEMM1: 256x256 8-phase deep-pipelined bf16 GEMM (T3+T4 template) ====
// 8 waves (2Mx4N), per-wave out 128x64, BK=64, LDS 128KB [op][par][half][128][64].
// Iteration = 2 K-tiles = 8 phases. Phase: {ds-read A-frags (+B at ph0/4) ->
// stage 1 half-tile -> barrier -> lgkm(0)+sched_barrier -> 16 MFMA -> barrier}.
// Stage stream: ph0/1:A(2i+1) ph2/3:B(2i+2) ph4/5:A(2i+2) ph6/7:B(2i+3).
// Counted vmcnt(4) ONLY at ph3/ph7 (2 half-tiles stay in flight); vmcnt(0)
// only in the last iteration. Publish audit: ph3's vmcnt covers stages
// through ph1 (tile 2i+1 complete for ph4-7); ph7's covers through ph5
// (tile 2i+2 complete for next ph0-3). Overwrite audit: each buffer's last
// ds-read drains at its phase's lgkm(0) before that phase's closing barrier;
// the overwriting stage issues >=1 phase later. Swizzle: chunk^=(row&7) on
// both stage-source and ds_read (verified 0 conflicts r5-r9).
__global__ __launch_bounds__(512, 2) void k_gemm_in(
    const bf16* __restrict__ A, const bf16* __restrict__ B,
    bf16* __restrict__ Cb, int K, int Nreal, int ldc, int ntn) {
  __shared__ __align__(16) bf16 Al[2][2][128 * 64]; // [parity][half] 64 KB
  __shared__ __align__(16) bf16 Bl[2][2][128 * 64]; // 64 KB
  const int tid = threadIdx.x;
  const int lane = tid & 63, wid = tid >> 6;
  const int wr = wid >> 2, wc = wid & 3;
  const int lr = lane & 15, kb = lane >> 4;
  const int cpx = (int)gridDim.x >> 3;
  const int bid = ((int)blockIdx.x & 7) * cpx + ((int)blockIdx.x >> 3);
  const long n0 = (long)(bid % ntn) * 256;
  const long m0 = (long)(bid / ntn) * 256;

  f32x4 acc[8][4];
#pragma unroll
  for (int i = 0; i < 8; ++i)
#pragma unroll
    for (int j = 0; j < 4; ++j) acc[i][j] = (f32x4){0.f, 0.f, 0.f, 0.f};

  const int ntile = K >> 6;
  const int niter = K >> 7;

#define STG(P, dst, rowbase, kt)                                               \
  { _Pragma("unroll") for (int j = 0; j < 2; ++j) {                            \
      int idx = j * 512 + tid;                                                 \
      int line = idx >> 3, ch = (idx & 7) ^ (line & 7);                        \
      __builtin_amdgcn_global_load_lds(                                        \
          (const AS1 void*)((P) + ((rowbase) + line) * (long)K +               \
                            (long)(kt)*64 + ch * 8),                           \
          (AS3 void*)((char*)(dst) + idx * 16), 16, 0, 0);                     \
  } }
#define RD(bufptr, r, c)                                                       \
  (*(const bf16x8*)((const char*)(bufptr) + (r)*128 + (((c) ^ ((r)&7)) * 16)))

  // prologue: tile0 (A0,A1,B0,B1) + tile1 (B0,B1); wait tile0, 2 in flight
  STG(A, Al[0][0], m0, 0);
  STG(A, Al[0][1], m0 + 128, 0);
  STG(B, Bl[0][0], n0, 0);
  STG(B, Bl[0][1], n0 + 128, 0);
  STG(B, Bl[1][0], n0, 1);
  STG(B, Bl[1][1], n0 + 128, 1);
  asm volatile("s_waitcnt vmcnt(4)" ::: "memory");
  __builtin_amdgcn_s_barrier();

  bf16x8 bfr[4][2];

#define PHASE(PAR, PP, RDB_FLAG, STAGE_STMT, VM_STMT)                          \
  {                                                                            \
    if (RDB_FLAG) {                                                            \
      _Pragma("unroll") for (int nf = 0; nf < 4; ++nf) {                       \
        bfr[nf][0] = RD(Bl[PAR][wc >> 1], (wc & 1) * 64 + nf * 16 + lr, kb);   \
        bfr[nf][1] = RD(Bl[PAR][wc >> 1], (wc & 1) * 64 + nf * 16 + lr, 4 + kb); \
      }                                                                        \
    }                                                                          \
    bf16x8 af00 = RD(Al[PAR][wr], (2 * (PP)) * 16 + lr, kb);                   \
    bf16x8 af01 = RD(Al[PAR][wr], (2 * (PP)) * 16 + lr, 4 + kb);               \
    bf16x8 af10 = RD(Al[PAR][wr], (2 * (PP) + 1) * 16 + lr, kb);               \
    bf16x8 af11 = RD(Al[PAR][wr], (2 * (PP) + 1) * 16 + lr, 4 + kb);           \
    STAGE_STMT;                                                                \
    VM_STMT;                                                                   \
    __builtin_amdgcn_s_barrier();                                              \
    asm volatile("s_waitcnt lgkmcnt(0)" ::: "memory");                         \
    __builtin_amdgcn_sched_barrier(0);                                         \
    __builtin_amdgcn_s_setprio(1);                                             \
    _Pragma("unroll") for (int nf = 0; nf < 4; ++nf) {                         \
      acc[2 * (PP)][nf] = __builtin_amdgcn_mfma_f32_16x16x32_bf16(             \
          af00, bfr[nf][0], acc[2 * (PP)][nf], 0, 0, 0);                       \
      acc[2 * (PP)][nf] = __builtin_amdgcn_mfma_f32_16x16x32_bf16(             \
          af01, bfr[nf][1], acc[2 * (PP)][nf], 0, 0, 0);                       \
      acc[2 * (PP) + 1][nf] = __builtin_amdgcn_mfma_f32_16x16x32_bf16(         \
          af10, bfr[nf][0], acc[2 * (PP) + 1][nf], 0, 0, 0);                   \
      acc[2 * (PP) + 1][nf] = __builtin_amdgcn_mfma_f32_16x16x32_bf16(         \
          af11, bfr[nf][1], acc[2 * (PP) + 1][nf], 0, 0, 0);                   \
    }                                                                          \
    __builtin_amdgcn_s_setprio(0);                                             \
    __builtin_amdgcn_s_barrier();                                              \
  }

  for (int i = 0; i < niter; ++i) {
    const int t1 = 2 * i + 1, t2 = 2 * i + 2, t3 = 2 * i + 3;
    const bool g2 = t2 < ntile, g3 = t3 < ntile;
    PHASE(0, 0, 1, STG(A, Al[1][0], m0, t1), );
    PHASE(0, 1, 0, STG(A, Al[1][1], m0 + 128, t1), );
    PHASE(0, 2, 0, if (g2) STG(B, Bl[0][0], n0, t2), );
    PHASE(0, 3, 0, if (g2) STG(B, Bl[0][1], n0 + 128, t2),
          if (g2) { asm volatile("s_waitcnt vmcnt(4)" ::: "memory"); }
          else { asm volatile("s_waitcnt vmcnt(0)" ::: "memory"); });
    PHASE(1, 0, 1, if (g2) STG(A, Al[0][0], m0, t2), );
    PHASE(1, 1, 0, if (g2) STG(A, Al[0][1], m0 + 128, t2), );
    PHASE(1, 2, 0, if (g3) STG(B, Bl[1][0], n0, t3), );
    PHASE(1, 3, 0, if (g3) STG(B, Bl[1][1], n0 + 128, t3),
          if (g3) { asm volatile("s_waitcnt vmcnt(4)" ::: "memory"); });
  }
#undef PHASE
#undef STG
#undef RD

  // epilogue: LDS-transpose full-line stores (reuse Al region as scratch)
  __syncthreads();
  bf16* scr = &Al[0][0][0] + wid * (16 * 72);
  const int rr = kb * 4;
  const int srow = lane >> 2, cg = lane & 3;
#pragma unroll
  for (int mf = 0; mf < 8; ++mf) {
#pragma unroll
    for (int nf = 0; nf < 4; ++nf)
#pragma unroll
      for (int j = 0; j < 4; ++j)
        scr[(rr + j) * 72 + nf * 16 + lr] = (bf16)acc[mf][nf][j];
    asm volatile("s_waitcnt lgkmcnt(0)" ::: "memory");
    __builtin_amdgcn_sched_barrier(0);
    int col = (int)n0 + wc * 64 + cg * 16;
    if (col < Nreal) {
      long grow = m0 + wr * 128 + mf * 16 + srow;
      bf16x8 v0 = *(const bf16x8*)(scr + srow * 72 + cg * 16);
      bf16x8 v1 = *(const bf16x8*)(scr + srow * 72 + cg * 16 + 8);
      *(bf16x8*)(Cb + grow * (long)ldc + col) = v0;
      *(bf16x8*)(Cb + grow * (long)ldc + col + 8) = v1;
    }
    __builtin_amdgcn_sched_barrier(0);
  }
}

// ====== bf16 GEMM body (r8-proven): BK=32, 3-buf distance-2 counted vmcnt ===
template <int WM, int WN, int NF, bool FUSE>
DEV void gemm_body(bf16* lds, float* rs2s,
                   const bf16* __restrict__ A, const bf16* __restrict__ B,
                   bf16* __restrict__ Cb, const float* __restrict__ xres,
                   const float* __restrict__ rs, const float* __restrict__ nw,
                   const float* __restrict__ pfm, float* __restrict__ outf,
                   int K, int Nreal, int ldc, int ntn) {
  constexpr int THREADS = WM * WN * 64;
  constexpr int BM = WM * 64;
  constexpr int BN = WN * NF * 16;
  constexpr int NA = (BM * 4) / THREADS;
  constexpr int NB = (BN * 4) / THREADS;
  constexpr int VMN = NA + NB; // loads per stage per thread
  constexpr int ASZ = (BM / 2) * 64;
  constexpr int BSZ = (BN / 2) * 64;
  const int tid = threadIdx.x;
  const int lane = tid & 63, wid = tid >> 6;
  const int wr = wid / WN, wc = wid % WN;
  const int lr = lane & 15, kb = lane >> 4;
  const int cpx = (int)gridDim.x >> 3;
  const int bid = ((int)blockIdx.x & 7) * cpx + ((int)blockIdx.x >> 3);
  const long n0 = (long)(bid % ntn) * BN;
  const long m0 = (long)(bid / ntn) * BM;

  f32x4 acc[4][NF];
#pragma unroll
  for (int i = 0; i < 4; ++i)
#pragma unroll
    for (int j = 0; j < NF; ++j) acc[i][j] = (f32x4){0.f, 0.f, 0.f, 0.f};
  float ssq[4] = {0.f, 0.f, 0.f, 0.f};

  const int nkt = K >> 5;

#define STAGE(pp, kt)                                                          \
  {                                                                            \
    const long koff = (long)(kt)*32;                                           \
    _Pragma("unroll") for (int j = 0; j < NA; ++j) {                           \
      int idx = j * THREADS + tid;                                             \
      int line = idx >> 3, sp = (idx & 7) ^ (line & 7);                        \
      int row = line * 2 + (sp >> 2), ch = sp & 3;                             \
      __builtin_amdgcn_global_load_lds(                                        \
          (const AS1 void*)(A + (m0 + row) * K + koff + ch * 8),               \
          (AS3 void*)((char*)(lds + (pp)*ASZ) + idx * 16), 16, 0, 0);          \
    }                                                                          \
    _Pragma("unroll") for (int j = 0; j < NB; ++j) {                           \
      int idx = j * THREADS + tid;                                             \
      int line = idx >> 3, sp = (idx & 7) ^ (line & 7);                        \
      int row = line * 2 + (sp >> 2), ch = sp & 3;                             \
      __builtin_amdgcn_global_load_lds(                                        \
          (const AS1 void*)(B + (n0 + row) * K + koff + ch * 8),               \
          (AS3 void*)((char*)(lds + 3 * ASZ + (pp)*BSZ) + idx * 16), 16, 0, 0);\
    }                                                                          \
  }
#define LOFF(r) (((r) >> 1) * 128 + (((((r)&1) << 2) | kb) ^ (((r) >> 1) & 7)) * 16)
#define RDA(pp, r) (*(const bf16x8*)((const char*)(lds + (pp)*ASZ) + LOFF(r)))
#define RDB(pp, r) (*(const bf16x8*)((const char*)(lds + 3 * ASZ + (pp)*BSZ) + LOFF(r)))

  STAGE(0, 0);
  STAGE(1, 1);

  int cur = 0;
  for (int t = 0; t < nkt; ++t) {
    if (t + 2 < nkt) {
      int sb = cur + 2; if (sb >= 3) sb -= 3;
      STAGE(sb, t + 2);
      if constexpr (VMN == 3) asm volatile("s_waitcnt vmcnt(6)" ::: "memory");
      else asm volatile("s_waitcnt vmcnt(8)" ::: "memory");
    } else if (t + 1 < nkt) {
      if constexpr (VMN == 3) asm volatile("s_waitcnt vmcnt(3)" ::: "memory");
      else asm volatile("s_waitcnt vmcnt(4)" ::: "memory");
    } else {
      asm volatile("s_waitcnt vmcnt(0)" ::: "memory");
    }
    __builtin_amdgcn_s_barrier();

    bf16x8 af[4], bv[NF];
#pragma unroll
    for (int mf = 0; mf < 4; ++mf) af[mf] = RDA(cur, wr * 64 + mf * 16 + lr);
#pragma unroll
    for (int nf = 0; nf < NF; ++nf) bv[nf] = RDB(cur, wc * (NF * 16) + nf * 16 + lr);
    asm volatile("s_waitcnt lgkmcnt(0)" ::: "memory");
    __builtin_amdgcn_sched_barrier(0);
    __builtin_amdgcn_s_barrier();

    if constexpr (FUSE) {
      if (wc == 0) {
#pragma unroll
        for (int mf = 0; mf < 4; ++mf)
#pragma unroll
          for (int e = 0; e < 8; ++e) {
            float f = (float)af[mf][e];
            ssq[mf] = fmaf(f, f, ssq[mf]);
          }
      }
    }
    __builtin_amdgcn_s_setprio(1);
#pragma unroll
    for (int mf = 0; mf < 4; ++mf)
#pragma unroll
      for (int nf = 0; nf < NF; ++nf)
        acc[mf][nf] = __builtin_amdgcn_mfma_f32_16x16x32_bf16(af[mf], bv[nf],
                                                              acc[mf][nf], 0, 0, 0);
    __builtin_amdgcn_s_setprio(0);
    cur = cur + 1 == 3 ? 0 : cur + 1;
  }
#undef STAGE
#undef LOFF
#undef RDA
#undef RDB

  const int rr = kb * 4;
  if constexpr (FUSE) {
    if (wc == 0) {
#pragma unroll
      for (int mf = 0; mf < 4; ++mf) {
        float v = ssq[mf];
        v += __shfl_xor(v, 16);
        v += __shfl_xor(v, 32);
        if (kb == 0) rs2s[wr * 64 + mf * 16 + lr] = rsqrtf(v * (1.f / kDInner) + kGnEps);
      }
    }
    __syncthreads();
    const int bx = (int)(m0 >> 11);
    const float pf = pfm[bx], pm = pfm[4 + bx];
#pragma unroll
    for (int mf = 0; mf < 4; ++mf) {
      long rbase = m0 + wr * 64 + mf * 16 + rr;
      float rsv[4], r2v[4];
#pragma unroll
      for (int j = 0; j < 4; ++j) {
        rsv[j] = rs[rbase + j];
        r2v[j] = rs2s[wr * 64 + mf * 16 + rr + j];
      }
#pragma unroll
      for (int nf = 0; nf < NF; ++nf) {
        int col = (int)n0 + wc * (NF * 16) + nf * 16 + lr;
        float wv = nw[col];
#pragma unroll
        for (int j = 0; j < 4; ++j) {
          size_t oi = (size_t)(rbase + j) * kDModel + col;
          float xv = xres[oi];
          outf[oi] = xv + pf * xv * rsv[j] * wv + pm * r2v[j] * acc[mf][nf][j];
        }
      }
    }
  } else {
    __syncthreads();
    bf16* scr = lds + wid * (16 * 72);
    const int srow = lane >> 2, cg = lane & 3;
#pragma unroll
    for (int mf = 0; mf < 4; ++mf) {
#pragma unroll
      for (int nf = 0; nf < NF; ++nf)
#pragma unroll
        for (int j = 0; j < 4; ++j)
          scr[(rr + j) * 72 + nf * 16 + lr] = (bf16)acc[mf][nf][j];
      asm volatile("s_waitcnt lgkmcnt(0)" ::: "memory");
      __builtin_amdgcn_sched_barrier(0);
      int col = (int)n0 + wc * (NF * 16) + cg * 16;
      if (col < Nreal) {
        long grow = m0 + wr * 64 + mf * 16 + srow;
        bf16x8 v0 = *(const bf16x8*)(scr + srow * 72 + cg * 16);
        bf16x8 v1 = *(const bf16x8*)(scr + srow * 72 + cg * 16 + 8);
        *(bf16x8*)(Cb + grow * (long)ldc + col) = v0;
        *(bf16x8*)(Cb + grow * (long)ldc + col + 8) = v1;
      }
      __builtin_amdgcn_sched_barrier(0);
    }
  }
}

// GEMM2: out = x + pf*x_norm + pm*rs2*(g @ w2g^T)  (BM=64, BN=128, 4 waves)
__global__ __launch_bounds__(256, 4) void k_gemm_out(
    const bf16* __restrict__ A, const bf16* __restrict__ B,
    const float* __restrict__ xres, const float* __restrict__ rs,
    const float* __restrict__ nw, const float* __restrict__ pfm,
    float* __restrict__ outf, int K, int Nreal, int ldc, int ntn) {
  constexpr int ASZ = (64 / 2) * 64, BSZ = (128 / 2) * 64;
  __shared__ __align__(16) bf16 lds[3 * ASZ + 3 * BSZ];
  __shared__ float rs2s[64];
  gemm_body<1, 4, 2, true>(lds, rs2s, A, B, nullptr, xres, rs, nw, pfm, outf,
                           K, Nreal, ldc, ntn);
}

// ------- conv1d (k=4) + bias + SiLU (bf16x8) AND dt/ldA, one launch ---------
__global__ __launch_bounds__(256) void k_convdt(const bf16* __restrict__ zx,
                                                const float* __restrict__ cw,
                                                const float* __restrict__ cb,
                                                bf16* __restrict__ xbc,
                                                const float* __restrict__ dt_bias,
                                                const float* __restrict__ A_log,
                                                float* __restrict__ dt,
                                                float* __restrict__ ldA) {
  const int gid = blockIdx.x * 256 + threadIdx.x;
  if (gid < kRows * 272) { // conv: 272 = 2176/8 chunks per row
    const int row = gid / 272;
    const int cg = gid - row * 272;
    const int c0 = cg * 8;
    const int s = row & (kSeq - 1);
    const bf16* base = zx + (size_t)row * kDInProj + kDInner + c0;
    bf16x8 z8 = {};
    bf16x8 r3 = *(const bf16x8*)(base);
    bf16x8 r2 = (s >= 1) ? *(const bf16x8*)(base - kDInProj) : z8;
    bf16x8 r1 = (s >= 2) ? *(const bf16x8*)(base - 2 * kDInProj) : z8;
    bf16x8 r0 = (s >= 3) ? *(const bf16x8*)(base - 3 * kDInProj) : z8;
    bf16x8 o;
#pragma unroll
    for (int e = 0; e < 8; ++e) {
      float4 w = ((const float4*)cw)[c0 + e];
      float a = cb[c0 + e] + w.x * (float)r0[e] + w.y * (float)r1[e] +
                w.z * (float)r2[e] + w.w * (float)r3[e];
      o[e] = (bf16)siluf(a);
    }
    *(bf16x8*)(xbc + (size_t)row * kConvDim + c0) = o;
  } else { // dt path: kRows*4 threads
    const int g2 = gid - kRows * 272;
    const int row = g2 >> 2, grp = g2 & 3;
    bf16x8 r8 = *(const bf16x8*)(zx + (size_t)row * kDInProj + (kDInner + kConvDim) + grp * 8);
#pragma unroll
    for (int e = 0; e < 8; ++e) {
      int hh = grp * 8 + e;
      float raw = (float)r8[e] + dt_bias[hh];
      float dtv = (raw > 20.f) ? raw : log1pf(expf(raw));
      dt[row * kHeads + hh] = dtv;
      ldA[row * kHeads + hh] = dtv * -expf(A_log[hh]);
    }
  }
}

// ================= chunked SSD scan =================
__global__ __launch_bounds__(256) void k_chunkA(
    const bf16* __restrict__ xbc, const float* __restrict__ dtb,
    const float* __restrict__ ldab, float* __restrict__ cumbuf,
    float* __restrict__ Tc, bf16* __restrict__ yb, bf16* __restrict__ Sbuf) {
  const int c = blockIdx.x, h = blockIdx.y, b = blockIdx.z;
  const int tid = threadIdx.x;
  const int w = tid >> 6, lane = tid & 63, lr = lane & 15, kb = lane >> 4;
  const int rr = kb * 4;
  const int t0 = c * kChunk;
  __shared__ bf16 Bl[64 * 72], Cl[64 * 72], XT[64 * 72], WBT[64 * 72], Ml[64 * 72];
  __shared__ float cum_s[64], dt_s[64], w_s[64];

  { // stage B, C (row-major) and X^T
    int s = tid >> 2, q = tid & 3;
    const bf16* rowp = xbc + ((size_t)b * kSeq + t0 + s) * kConvDim;
    bf16x8 x0 = *(const bf16x8*)(rowp + h * 64 + q * 16);
    bf16x8 x1 = *(const bf16x8*)(rowp + h * 64 + q * 16 + 8);
    bf16x8 b0 = *(const bf16x8*)(rowp + kDInner + q * 16);
    bf16x8 b1 = *(const bf16x8*)(rowp + kDInner + q * 16 + 8);
    bf16x8 c0 = *(const bf16x8*)(rowp + kDInner + 64 + q * 16);
    bf16x8 c1 = *(const bf16x8*)(rowp + kDInner + 64 + q * 16 + 8);
    *(bf16x8*)(Bl + s * 72 + q * 16) = b0;
    *(bf16x8*)(Bl + s * 72 + q * 16 + 8) = b1;
    *(bf16x8*)(Cl + s * 72 + q * 16) = c0;
    *(bf16x8*)(Cl + s * 72 + q * 16 + 8) = c1;
#pragma unroll
    for (int e = 0; e < 8; ++e) XT[(q * 16 + e) * 72 + s] = x0[e];
#pragma unroll
    for (int e = 0; e < 8; ++e) XT[(q * 16 + 8 + e) * 72 + s] = x1[e];
  }
  if (tid < 64) { // wave 0: inclusive prefix of ldA
    size_t di = ((size_t)b * kSeq + t0 + tid) * kHeads + h;
    float v = ldab[di];
    float dtv = dtb[di];
#pragma unroll
    for (int o = 1; o < 64; o <<= 1) {
      float u = __shfl_up(v, o);
      if (lane >= o) v += u;
    }
    cum_s[tid] = v;
    dt_s[tid] = dtv;
    float tot = __shfl(v, 63);
    w_s[tid] = expf(tot - v) * dtv;
    cumbuf[(((size_t)b * kHeads + h) * kNChunk + c) * 64 + tid] = v;
    if (tid == 63) Tc[(b * kHeads + h) * kNChunk + c] = expf(v);
  }
  __syncthreads();

  // WBT[n][s] = B[s][n] * w[s]
#pragma unroll
  for (int i = 0; i < 16; ++i) {
    int e = i * 256 + tid;
    int n = e >> 6, s = e & 63;
    WBT[n * 72 + s] = (bf16)((float)Bl[s * 72 + n] * w_s[s]);
  }

  // GEMM1: G[t,s] = sum_n C[t,n] B[s,n]
  f32x4 g[4];
#pragma unroll
  for (int nt = 0; nt < 4; ++nt) g[nt] = (f32x4){0.f, 0.f, 0.f, 0.f};
#pragma unroll
  for (int kk = 0; kk < 2; ++kk) {
    bf16x8 a = *(const bf16x8*)(Cl + (w * 16 + lr) * 72 + kk * 32 + kb * 8);
#pragma unroll
    for (int nt = 0; nt < 4; ++nt) {
      bf16x8 bb = *(const bf16x8*)(Bl + (nt * 16 + lr) * 72 + kk * 32 + kb * 8);
      g[nt] = __builtin_amdgcn_mfma_f32_16x16x32_bf16(a, bb, g[nt], 0, 0, 0);
    }
  }
#pragma unroll
  for (int nt = 0; nt < 4; ++nt)
#pragma unroll
    for (int j = 0; j < 4; ++j) {
      int tt = w * 16 + rr + j, ss = nt * 16 + lr;
      float m = (ss <= tt) ? g[nt][j] * expf(cum_s[tt] - cum_s[ss]) * dt_s[ss] : 0.f;
      Ml[tt * 72 + ss] = (bf16)m;
    }
  __syncthreads();

  // GEMM2: Y_intra[t,p] = sum_s M[t,s] x[s,p]
  f32x4 y4[4];
#pragma unroll
  for (int pt = 0; pt < 4; ++pt) y4[pt] = (f32x4){0.f, 0.f, 0.f, 0.f};
#pragma unroll
  for (int kk = 0; kk < 2; ++kk) {
    bf16x8 a = *(const bf16x8*)(Ml + (w * 16 + lr) * 72 + kk * 32 + kb * 8);
#pragma unroll
    for (int pt = 0; pt < 4; ++pt) {
      bf16x8 bb = *(const bf16x8*)(XT + (pt * 16 + lr) * 72 + kk * 32 + kb * 8);
      y4[pt] = __builtin_amdgcn_mfma_f32_16x16x32_bf16(a, bb, y4[pt], 0, 0, 0);
    }
  }
  // GEMM3: S[p,n] = sum_s x[s,p] w[s] B[s,n]
  f32x4 s4[4];
#pragma unroll
  for (int nt = 0; nt < 4; ++nt) s4[nt] = (f32x4){0.f, 0.f, 0.f, 0.f};
#pragma unroll
  for (int kk = 0; kk < 2; ++kk) {
    bf16x8 a = *(const bf16x8*)(XT + (w * 16 + lr) * 72 + kk * 32 + kb * 8);
#pragma unroll
    for (int nt = 0; nt < 4; ++nt) {
      bf16x8 bb = *(const bf16x8*)(WBT + (nt * 16 + lr) * 72 + kk * 32 + kb * 8);
      s4[nt] = __builtin_amdgcn_mfma_f32_16x16x32_bf16(a, bb, s4[nt], 0, 0, 0);
    }
  }
  // Bl/Cl dead -> transpose scratch for y (Bl) and S (Cl)
#pragma unroll
  for (int pt = 0; pt < 4; ++pt)
#pragma unroll
    for (int j = 0; j < 4; ++j) {
      Bl[(w * 16 + rr + j) * 72 + pt * 16 + lr] = (bf16)y4[pt][j];
      Cl[(w * 16 + rr + j) * 72 + pt * 16 + lr] = (bf16)s4[pt][j];
    }
  __syncthreads();
  {
    int row = tid >> 2, cg = tid & 3;
    bf16x8 v0 = *(const bf16x8*)(Bl + row * 72 + cg * 16);
    bf16x8 v1 = *(const bf16x8*)(Bl + row * 72 + cg * 16 + 8);
    bf16* dst = yb + ((size_t)b * kSeq + t0 + row) * kDInner + h * 64 + cg * 16;
    *(bf16x8*)dst = v0;
    *(bf16x8*)(dst + 8) = v1;
    const size_t sbase = (((size_t)b * kHeads + h) * kNChunk + c) * 4096;
    bf16x8 u0 = *(const bf16x8*)(Cl + row * 72 + cg * 16);
    bf16x8 u1 = *(const bf16x8*)(Cl + row * 72 + cg * 16 + 8);
    bf16* sdst = Sbuf + sbase + row * 64 + cg * 16;
    *(bf16x8*)sdst = u0;
    *(bf16x8*)(sdst + 8) = u1;
  }
}

// Pass B: serial scan over 32 chunks, in-place (bf16 states, fp32 accum)
__global__ __launch_bounds__(256) void k_chunkB(bf16* __restrict__ S,
                                                const float* __restrict__ Tc) {
  const int gid = blockIdx.x * 256 + threadIdx.x;
  const int bh = gid >> 10;
  const int pn = (gid & 1023) << 2;
  bf16* base = S + (size_t)bh * kNChunk * 4096 + pn;
  const float* tc = Tc + bh * kNChunk;
  float4 hh = {0.f, 0.f, 0.f, 0.f};
  bf16x4 s = *(const bf16x4*)(base);
  for (int c = 0; c < kNChunk; ++c) {
    bf16x4 sn = {};
    if (c + 1 < kNChunk) sn = *(const bf16x4*)(base + (size_t)(c + 1) * 4096);
    float t = tc[c];
    bf16x4 ho;
    ho[0] = (bf16)hh.x; ho[1] = (bf16)hh.y; ho[2] = (bf16)hh.z; ho[3] = (bf16)hh.w;
    *(bf16x4*)(base + (size_t)c * 4096) = ho;
    hh.x = t * hh.x + (float)s[0];
    hh.y = t * hh.y + (float)s[1];
    hh.z = t * hh.z + (float)s[2];
    hh.w = t * hh.w + (float)s[3];
    s = sn;
  }
}

// Pass C: yfull = y_intra + exp(cum)*C·h0 + D*x ; writes g = yfull*silu(z)
__global__ __launch_bounds__(256) void k_chunkC(
    const bf16* __restrict__ xbc, const bf16* __restrict__ zx,
    const float* __restrict__ cumbuf, const bf16* __restrict__ hs,
    const float* __restrict__ Dp, bf16* __restrict__ yb) {
  const int c = blockIdx.x, h = blockIdx.y, b = blockIdx.z;
  const int tid = threadIdx.x;
  const int w = tid >> 6, lane = tid & 63, lr = lane & 15, kb = lane >> 4;
  const int rr = kb * 4;
  const int t0 = c * kChunk;
  __shared__ bf16 Cl[64 * 72];
  __shared__ float ecum[64];
  __shared__ float scrf[64 * 68];
  {
    int s = tid >> 2, q = tid & 3;
    const bf16* rowp = xbc + ((size_t)b * kSeq + t0 + s) * kConvDim + kDInner + 64 + q * 16;
    *(bf16x8*)(Cl + s * 72 + q * 16) = *(const bf16x8*)rowp;
    *(bf16x8*)(Cl + s * 72 + q * 16 + 8) = *(const bf16x8*)(rowp + 8);
  }
  if (tid < 64)
    ecum[tid] = expf(cumbuf[(((size_t)b * kHeads + h) * kNChunk + c) * 64 + tid]);
  __syncthreads();

  const bf16* hbase = hs + (((size_t)b * kHeads + h) * kNChunk + c) * 4096;
  f32x4 acc[4];
#pragma unroll
  for (int pt = 0; pt < 4; ++pt) acc[pt] = (f32x4){0.f, 0.f, 0.f, 0.f};
#pragma unroll
  for (int kk = 0; kk < 2; ++kk) {
    bf16x8 a = *(const bf16x8*)(Cl + (w * 16 + lr) * 72 + kk * 32 + kb * 8);
#pragma unroll
    for (int pt = 0; pt < 4; ++pt) {
      bf16x8 bb = *(const bf16x8*)(hbase + (pt * 16 + lr) * 64 + kk * 32 + kb * 8);
      acc[pt] = __builtin_amdgcn_mfma_f32_16x16x32_bf16(a, bb, acc[pt], 0, 0, 0);
    }
  }
#pragma unroll
  for (int pt = 0; pt < 4; ++pt)
#pragma unroll
    for (int j = 0; j < 4; ++j) {
      int tt = w * 16 + rr + j;
      scrf[tt * 68 + pt * 16 + lr] = ecum[tt] * acc[pt][j];
    }
  __syncthreads();
  {
    const float Dh = Dp[h];
    int row = tid >> 2, cg = tid & 3;
    size_t ri = (size_t)b * kSeq + t0 + row;
    const float* sp = scrf + row * 68 + cg * 16;
    bf16* yp = yb + ri * kDInner + h * 64 + cg * 16;
    const bf16* xp = xbc + ri * kConvDim + h * 64 + cg * 16;
    const bf16* zp = zx + ri * kDInProj + h * 64 + cg * 16;
#pragma unroll
    for (int half = 0; half < 2; ++half) {
      bf16x8 yv = *(const bf16x8*)(yp + half * 8);
      bf16x8 xv = *(const bf16x8*)(xp + half * 8);
      bf16x8 zv = *(const bf16x8*)(zp + half * 8);
      bf16x8 o;
#pragma unroll
      for (int e = 0; e < 8; ++e) {
        float yfull = (float)yv[e] + sp[half * 8 + e] + Dh * (float)xv[e];
        o[e] = (bf16)(yfull * siluf((float)zv[e]));
      }
      *(bf16x8*)(yp + half * 8) = o;
    }
  }
}

extern "C" void kernel_launch(void* const* d_in, const int* in_sizes, int n_in,
                              void* d_out, int out_size, void* d_ws, size_t ws_size,
                              hipStream_t stream) {
  const float* x = (const float*)d_in[0];
  const float* norm_w = (const float*)d_in[1];
  const float* r_w1 = (const float*)d_in[2];
  const float* r_b1 = (const float*)d_in[3];
  const float* r_w2 = (const float*)d_in[4];
  const float* r_b2 = (const float*)d_in[5];
  const float* in_proj_w = (const float*)d_in[6];
  const float* conv_w = (const float*)d_in[7];
  const float* conv_b = (const float*)d_in[8];
  const float* dt_bias = (const float*)d_in[9];
  const float* A_log = (const float*)d_in[10];
  const float* D_param = (const float*)d_in[11];
  const float* gnorm_w = (const float*)d_in[12];
  const float* out_proj_w = (const float*)d_in[13];
  float* out = (float*)d_out;
  char* ws = (char*)d_ws;

  // workspace layout (~207 MB)
  bf16* xnb     = (bf16*)(ws + 0);           // 16,777,216
  bf16* w1b     = (bf16*)(ws + 16777216);    //  8,912,896
  bf16* zx      = (bf16*)(ws + 25690112);    // 69,730,304
  bf16* xbc     = (bf16*)(ws + 95420416);    // 35,651,584
  float* dtb    = (float*)(ws + 131072000);  //  1,048,576
  float* ldab   = (float*)(ws + 132120576);  //  1,048,576
  float* cumbuf = (float*)(ws + 133169152);  //  1,048,576
  float* Tcb    = (float*)(ws + 134217728);  //     16,384
  bf16* yb      = (bf16*)(ws + 134234112);   // 33,554,432 (y -> g in place)
  bf16* Sbuf    = (bf16*)(ws + 167788544);   // 33,554,432
  bf16* w2b     = (bf16*)(ws + 201342976);   //  4,194,304
  float* part   = (float*)(ws + 205537280);  //  1,048,576
  float* meanb  = (float*)(ws + 206585856);  //     16,384
  float* pfm    = (float*)(ws + 206602240);  //        128
  float* rsb    = (float*)(ws + 206602368);  //     32,768

  k_pre<<<kRows + kW1Blocks + kW2Blocks, 256, 0, stream>>>(
      x, norm_w, xnb, rsb, in_proj_w, w1b, out_proj_w, gnorm_w, w2b);
  k_pool1<<<dim3(64, 4), 128, 0, stream>>>(xnb, part);
  k_pool2<<<16, 256, 0, stream>>>(part, meanb);
  k_router<<<1, 128, 0, stream>>>(meanb, r_w1, r_b1, r_w2, r_b2, pfm);
  // zxbcdt = x_norm @ in_proj_w.T  [8192 x 4256] ; 256x256 tiles: 32*17=544
  k_gemm_in<<<(kRows / 256) * (kNPad1 / 256), 512, 0, stream>>>(
      xnb, w1b, zx, kDModel, kDInProj, kDInProj, kNPad1 / 256);
  k_convdt<<<(kRows * 272 + kRows * 4) / 256, 256, 0, stream>>>(
      zx, conv_w, conv_b, xbc, dt_bias, A_log, dtb, ldab);
  k_chunkA<<<dim3(kNChunk, kHeads, kBatch), 256, 0, stream>>>(
      xbc, dtb, ldab, cumbuf, Tcb, yb, Sbuf);
  k_chunkB<<<512, 256, 0, stream>>>(Sbuf, Tcb);
  k_chunkC<<<dim3(kNChunk, kHeads, kBatch), 256, 0, stream>>>(
      xbc, zx, cumbuf, Sbuf, D_param, yb);
  // out = x + pf*x_norm + pm*rs2*(g @ (out_proj_w*gw).T); rs2 fused in-kernel
  k_gemm_out<<<(kRows / 64) * (kDModel / 128), 256, 0, stream>>>(
      yb, w2b, x, rsb, norm_w, pfm, out,
      kDInner, kDModel, kDModel, kDModel / 128);
}

// Round 11
// 343.424 us; speedup vs baseline: 1.0365x; 1.0365x over previous
//
#include <hip/hip_runtime.h>
#include <math.h>

typedef __bf16 bf16;
typedef __bf16 bf16x8 __attribute__((ext_vector_type(8)));
typedef __bf16 bf16x4 __attribute__((ext_vector_type(4)));
typedef float f32x4 __attribute__((ext_vector_type(4)));

#define DEV static __device__ __forceinline__
#define AS1 __attribute__((address_space(1)))
#define AS3 __attribute__((address_space(3)))

constexpr int kBatch = 4, kSeq = 2048, kDModel = 1024;
constexpr int kDInner = 2048, kHeads = 32;
constexpr int kConvDim = 2176, kDInProj = 4256, kNPad1 = 4352;
constexpr int kRows = kBatch * kSeq; // 8192
constexpr int kChunk = 64, kNChunk = kSeq / kChunk; // 32
constexpr float kRmsEps = 1.1920929e-07f;
constexpr float kGnEps = 1e-5f;
constexpr int kW1Blocks = kNPad1 * kDModel / 256;   // 17408
constexpr int kW2Blocks = kDModel * kDInner / 1024; // 2048

DEV float siluf(float x) { return x / (1.f + expf(-x)); }

DEV float block_reduce_sum(float v, float* red, int tid) {
#pragma unroll
  for (int m = 1; m < 64; m <<= 1) v += __shfl_xor(v, m);
  if ((tid & 63) == 0) red[tid >> 6] = v;
  __syncthreads();
  return red[0] + red[1] + red[2] + red[3];
}

// ------ fused prologue: RMSNorm (+row scale) | w1 cast+pad | w2*gw cast ------
__global__ __launch_bounds__(256) void k_pre(
    const float* __restrict__ x, const float* __restrict__ nw,
    bf16* __restrict__ xnb, float* __restrict__ rs,
    const float* __restrict__ w1, bf16* __restrict__ w1b,
    const float* __restrict__ w2, const float* __restrict__ gw,
    bf16* __restrict__ w2b) {
  const int blk = blockIdx.x;
  const int tid = threadIdx.x;
  if (blk < kRows) { // RMSNorm row
    const int row = blk;
    float4 v = ((const float4*)(x + (size_t)row * kDModel))[tid];
    __shared__ float red[4];
    float ss = block_reduce_sum(v.x * v.x + v.y * v.y + v.z * v.z + v.w * v.w, red, tid);
    float scale = rsqrtf(ss * (1.f / kDModel) + kRmsEps);
    if (tid == 0) rs[row] = scale;
    float4 wv = ((const float4*)nw)[tid];
    bf16x4 ov;
    ov[0] = (bf16)(v.x * scale * wv.x);
    ov[1] = (bf16)(v.y * scale * wv.y);
    ov[2] = (bf16)(v.z * scale * wv.z);
    ov[3] = (bf16)(v.w * scale * wv.w);
    *(bf16x4*)(xnb + (size_t)row * kDModel + tid * 4) = ov;
  } else if (blk < kRows + kW1Blocks) { // w1 cast + zero-pad rows >= 4256
    const size_t idx = (size_t)(blk - kRows) * 256 + tid;
    const int row = (int)(idx >> 10);
    w1b[idx] = (bf16)(row < kDInProj ? w1[idx] : 0.f);
  } else { // w2b[n,k] = w2[n,k] * gw[k]
    const size_t i4 = (size_t)(blk - kRows - kW1Blocks) * 256 + tid;
    const int k4 = (int)((i4 * 4) & (kDInner - 1));
    float4 v = ((const float4*)w2)[i4];
    float4 g = *(const float4*)(gw + k4);
    bf16x4 o;
    o[0] = (bf16)(v.x * g.x); o[1] = (bf16)(v.y * g.y);
    o[2] = (bf16)(v.z * g.z); o[3] = (bf16)(v.w * g.w);
    ((bf16x4*)w2b)[i4] = o;
  }
}

// ---------------- mean pool over S (deterministic 2-stage) ----------------
__global__ __launch_bounds__(128) void k_pool1(const bf16* __restrict__ xnb,
                                               float* __restrict__ part) {
  const int g = blockIdx.x, b = blockIdx.y;
  const int tid = threadIdx.x;
  const bf16* base = xnb + ((size_t)b * kSeq + (size_t)g * 32) * kDModel + tid * 8;
  float acc[8] = {0, 0, 0, 0, 0, 0, 0, 0};
  for (int r = 0; r < 32; ++r) {
    bf16x8 v = *(const bf16x8*)(base + (size_t)r * kDModel);
#pragma unroll
    for (int j = 0; j < 8; ++j) acc[j] += (float)v[j];
  }
  float* o = part + ((size_t)b * 64 + g) * kDModel + tid * 8;
#pragma unroll
  for (int j = 0; j < 8; ++j) o[j] = acc[j];
}

__global__ __launch_bounds__(256) void k_pool2(const float* __restrict__ part,
                                               float* __restrict__ mean) {
  const int idx = blockIdx.x * 256 + threadIdx.x; // 4096
  const int b = idx >> 10, d = idx & 1023;
  float s = 0.f;
  for (int g = 0; g < 64; ++g) s += part[((size_t)b * 64 + g) * kDModel + d];
  mean[idx] = s * (1.f / kSeq);
}

// ---------------- router MLP + softmax ----------------
__global__ __launch_bounds__(128) void k_router(const float* __restrict__ mean,
                                                const float* __restrict__ w1,
                                                const float* __restrict__ b1,
                                                const float* __restrict__ w2,
                                                const float* __restrict__ b2,
                                                float* __restrict__ pfm) {
  __shared__ float hbuf[4][32];
  __shared__ float logit[4][3];
  const int t = threadIdx.x;
  {
    int b = t >> 5, j = t & 31;
    float s = b1[j];
    for (int d = 0; d < kDModel; ++d) s += mean[b * kDModel + d] * w1[j * kDModel + d];
    hbuf[b][j] = siluf(s);
  }
  __syncthreads();
  if (t < 12) {
    int b = t / 3, k = t % 3;
    float s = b2[k];
    for (int j = 0; j < 32; ++j) s += hbuf[b][j] * w2[k * 32 + j];
    logit[b][k] = s;
  }
  __syncthreads();
  if (t < 4) {
    float m = fmaxf(logit[t][0], fmaxf(logit[t][1], logit[t][2]));
    float e0 = expf(logit[t][0] - m), e1 = expf(logit[t][1] - m), e2 = expf(logit[t][2] - m);
    float inv = 1.f / (e0 + e1 + e2);
    pfm[t] = e0 * inv;            // p_fast[b]
    pfm[4 + t] = (e1 + e2) * inv; // p_mamba[b]
  }
}

// ====== bf16 GEMM body (r8/r9-proven): BK=32, 3-buf distance-2 counted vmcnt
template <int WM, int WN, int NF, bool FUSE>
DEV void gemm_body(bf16* lds, float* rs2s,
                   const bf16* __restrict__ A, const bf16* __restrict__ B,
                   bf16* __restrict__ Cb, const float* __restrict__ xres,
                   const float* __restrict__ rs, const float* __restrict__ nw,
                   const float* __restrict__ pfm, float* __restrict__ outf,
                   int K, int Nreal, int ldc, int ntn) {
  constexpr int THREADS = WM * WN * 64;
  constexpr int BM = WM * 64;
  constexpr int BN = WN * NF * 16;
  constexpr int NA = (BM * 4) / THREADS;
  constexpr int NB = (BN * 4) / THREADS;
  constexpr int VMN = NA + NB; // loads per stage per thread
  constexpr int ASZ = (BM / 2) * 64;
  constexpr int BSZ = (BN / 2) * 64;
  const int tid = threadIdx.x;
  const int lane = tid & 63, wid = tid >> 6;
  const int wr = wid / WN, wc = wid % WN;
  const int lr = lane & 15, kb = lane >> 4;
  const int cpx = (int)gridDim.x >> 3;
  const int bid = ((int)blockIdx.x & 7) * cpx + ((int)blockIdx.x >> 3);
  const long n0 = (long)(bid % ntn) * BN;
  const long m0 = (long)(bid / ntn) * BM;

  f32x4 acc[4][NF];
#pragma unroll
  for (int i = 0; i < 4; ++i)
#pragma unroll
    for (int j = 0; j < NF; ++j) acc[i][j] = (f32x4){0.f, 0.f, 0.f, 0.f};
  float ssq[4] = {0.f, 0.f, 0.f, 0.f};

  const int nkt = K >> 5;

#define STAGE(pp, kt)                                                          \
  {                                                                            \
    const long koff = (long)(kt)*32;                                           \
    _Pragma("unroll") for (int j = 0; j < NA; ++j) {                           \
      int idx = j * THREADS + tid;                                             \
      int line = idx >> 3, sp = (idx & 7) ^ (line & 7);                        \
      int row = line * 2 + (sp >> 2), ch = sp & 3;                             \
      __builtin_amdgcn_global_load_lds(                                        \
          (const AS1 void*)(A + (m0 + row) * K + koff + ch * 8),               \
          (AS3 void*)((char*)(lds + (pp)*ASZ) + idx * 16), 16, 0, 0);          \
    }                                                                          \
    _Pragma("unroll") for (int j = 0; j < NB; ++j) {                           \
      int idx = j * THREADS + tid;                                             \
      int line = idx >> 3, sp = (idx & 7) ^ (line & 7);                        \
      int row = line * 2 + (sp >> 2), ch = sp & 3;                             \
      __builtin_amdgcn_global_load_lds(                                        \
          (const AS1 void*)(B + (n0 + row) * K + koff + ch * 8),               \
          (AS3 void*)((char*)(lds + 3 * ASZ + (pp)*BSZ) + idx * 16), 16, 0, 0);\
    }                                                                          \
  }
#define LOFF(r) (((r) >> 1) * 128 + (((((r)&1) << 2) | kb) ^ (((r) >> 1) & 7)) * 16)
#define RDA(pp, r) (*(const bf16x8*)((const char*)(lds + (pp)*ASZ) + LOFF(r)))
#define RDB(pp, r) (*(const bf16x8*)((const char*)(lds + 3 * ASZ + (pp)*BSZ) + LOFF(r)))

  STAGE(0, 0);
  STAGE(1, 1);

  int cur = 0;
  for (int t = 0; t < nkt; ++t) {
    if (t + 2 < nkt) {
      int sb = cur + 2; if (sb >= 3) sb -= 3;
      STAGE(sb, t + 2);
      if constexpr (VMN == 3) asm volatile("s_waitcnt vmcnt(6)" ::: "memory");
      else asm volatile("s_waitcnt vmcnt(8)" ::: "memory");
    } else if (t + 1 < nkt) {
      if constexpr (VMN == 3) asm volatile("s_waitcnt vmcnt(3)" ::: "memory");
      else asm volatile("s_waitcnt vmcnt(4)" ::: "memory");
    } else {
      asm volatile("s_waitcnt vmcnt(0)" ::: "memory");
    }
    __builtin_amdgcn_s_barrier();

    bf16x8 bv[NF], af0, af1, af2, af3;
#pragma unroll
    for (int nf = 0; nf < NF; ++nf) bv[nf] = RDB(cur, wc * (NF * 16) + nf * 16 + lr);
    af0 = RDA(cur, wr * 64 + lr);
    __builtin_amdgcn_sched_barrier(0);
    af1 = RDA(cur, wr * 64 + 16 + lr);
    __builtin_amdgcn_sched_barrier(0);
    asm volatile("s_waitcnt lgkmcnt(1)" ::: "memory");
    __builtin_amdgcn_sched_barrier(0);
    __builtin_amdgcn_s_setprio(1);
#pragma unroll
    for (int nf = 0; nf < NF; ++nf)
      acc[0][nf] = __builtin_amdgcn_mfma_f32_16x16x32_bf16(af0, bv[nf], acc[0][nf], 0, 0, 0);
    af2 = RDA(cur, wr * 64 + 32 + lr);
    af3 = RDA(cur, wr * 64 + 48 + lr);
    __builtin_amdgcn_sched_barrier(0);
    asm volatile("s_waitcnt lgkmcnt(2)" ::: "memory");
    __builtin_amdgcn_sched_barrier(0);
#pragma unroll
    for (int nf = 0; nf < NF; ++nf)
      acc[1][nf] = __builtin_amdgcn_mfma_f32_16x16x32_bf16(af1, bv[nf], acc[1][nf], 0, 0, 0);
    asm volatile("s_waitcnt lgkmcnt(0)" ::: "memory");
    __builtin_amdgcn_sched_barrier(0);
    __builtin_amdgcn_s_barrier();
#pragma unroll
    for (int nf = 0; nf < NF; ++nf)
      acc[2][nf] = __builtin_amdgcn_mfma_f32_16x16x32_bf16(af2, bv[nf], acc[2][nf], 0, 0, 0);
#pragma unroll
    for (int nf = 0; nf < NF; ++nf)
      acc[3][nf] = __builtin_amdgcn_mfma_f32_16x16x32_bf16(af3, bv[nf], acc[3][nf], 0, 0, 0);
    __builtin_amdgcn_s_setprio(0);

    if constexpr (FUSE) {
      if (wc == 0) {
#pragma unroll
        for (int e = 0; e < 8; ++e) {
          float f0 = (float)af0[e], f1 = (float)af1[e];
          float f2 = (float)af2[e], f3 = (float)af3[e];
          ssq[0] = fmaf(f0, f0, ssq[0]);
          ssq[1] = fmaf(f1, f1, ssq[1]);
          ssq[2] = fmaf(f2, f2, ssq[2]);
          ssq[3] = fmaf(f3, f3, ssq[3]);
        }
      }
    }
    cur = cur + 1 == 3 ? 0 : cur + 1;
  }
#undef STAGE
#undef LOFF
#undef RDA
#undef RDB

  const int rr = kb * 4;
  if constexpr (FUSE) {
    if (wc == 0) {
#pragma unroll
      for (int mf = 0; mf < 4; ++mf) {
        float v = ssq[mf];
        v += __shfl_xor(v, 16);
        v += __shfl_xor(v, 32);
        if (kb == 0) rs2s[wr * 64 + mf * 16 + lr] = rsqrtf(v * (1.f / kDInner) + kGnEps);
      }
    }
    __syncthreads();
    const int bx = (int)(m0 >> 11);
    const float pf = pfm[bx], pm = pfm[4 + bx];
#pragma unroll
    for (int mf = 0; mf < 4; ++mf) {
      long rbase = m0 + wr * 64 + mf * 16 + rr;
      float rsv[4], r2v[4];
#pragma unroll
      for (int j = 0; j < 4; ++j) {
        rsv[j] = rs[rbase + j];
        r2v[j] = rs2s[wr * 64 + mf * 16 + rr + j];
      }
#pragma unroll
      for (int nf = 0; nf < NF; ++nf) {
        int col = (int)n0 + wc * (NF * 16) + nf * 16 + lr;
        float wv = nw[col];
#pragma unroll
        for (int j = 0; j < 4; ++j) {
          size_t oi = (size_t)(rbase + j) * kDModel + col;
          float xv = xres[oi];
          outf[oi] = xv + pf * xv * rsv[j] * wv + pm * r2v[j] * acc[mf][nf][j];
        }
      }
    }
  } else {
    __syncthreads();
    bf16* scr = lds + wid * (16 * 72);
    const int srow = lane >> 2, cg = lane & 3;
#pragma unroll
    for (int mf = 0; mf < 4; ++mf) {
#pragma unroll
      for (int nf = 0; nf < NF; ++nf)
#pragma unroll
        for (int j = 0; j < 4; ++j)
          scr[(rr + j) * 72 + nf * 16 + lr] = (bf16)acc[mf][nf][j];
      asm volatile("s_waitcnt lgkmcnt(0)" ::: "memory");
      __builtin_amdgcn_sched_barrier(0);
      int col = (int)n0 + wc * (NF * 16) + cg * 16;
      if (col < Nreal) {
        long grow = m0 + wr * 64 + mf * 16 + srow;
        bf16x8 v0 = *(const bf16x8*)(scr + srow * 72 + cg * 16);
        bf16x8 v1 = *(const bf16x8*)(scr + srow * 72 + cg * 16 + 8);
        *(bf16x8*)(Cb + grow * (long)ldc + col) = v0;
        *(bf16x8*)(Cb + grow * (long)ldc + col + 8) = v1;
      }
      __builtin_amdgcn_sched_barrier(0);
    }
  }
}

// GEMM1: zxbcdt = x_norm @ w1^T  (BM=128, BN=256, 8 waves)  [r9 proven 93us]
__global__ __launch_bounds__(512, 4) void k_gemm_in(
    const bf16* __restrict__ A, const bf16* __restrict__ B,
    bf16* __restrict__ Cb, int K, int Nreal, int ldc, int ntn) {
  constexpr int ASZ = (128 / 2) * 64, BSZ = (256 / 2) * 64;
  __shared__ __align__(16) bf16 lds[3 * ASZ + 3 * BSZ];
  __shared__ float rs2s[128];
  gemm_body<2, 4, 4, false>(lds, rs2s, A, B, Cb, nullptr, nullptr, nullptr,
                            nullptr, nullptr, K, Nreal, ldc, ntn);
}

// GEMM2: out = x + pf*x_norm + pm*rs2*(g @ w2g^T)  (BM=64, BN=128, 4 waves)
__global__ __launch_bounds__(256, 4) void k_gemm_out(
    const bf16* __restrict__ A, const bf16* __restrict__ B,
    const float* __restrict__ xres, const float* __restrict__ rs,
    const float* __restrict__ nw, const float* __restrict__ pfm,
    float* __restrict__ outf, int K, int Nreal, int ldc, int ntn) {
  constexpr int ASZ = (64 / 2) * 64, BSZ = (128 / 2) * 64;
  __shared__ __align__(16) bf16 lds[3 * ASZ + 3 * BSZ];
  __shared__ float rs2s[64];
  gemm_body<1, 4, 2, true>(lds, rs2s, A, B, nullptr, xres, rs, nw, pfm, outf,
                           K, Nreal, ldc, ntn);
}

// ------- conv1d (k=4) + bias + SiLU (bf16x8) AND dt/ldA, one launch ---------
__global__ __launch_bounds__(256) void k_convdt(const bf16* __restrict__ zx,
                                                const float* __restrict__ cw,
                                                const float* __restrict__ cb,
                                                bf16* __restrict__ xbc,
                                                const float* __restrict__ dt_bias,
                                                const float* __restrict__ A_log,
                                                float* __restrict__ dt,
                                                float* __restrict__ ldA) {
  const int gid = blockIdx.x * 256 + threadIdx.x;
  if (gid < kRows * 272) { // conv: 272 = 2176/8 chunks per row
    const int row = gid / 272;
    const int cg = gid - row * 272;
    const int c0 = cg * 8;
    const int s = row & (kSeq - 1);
    const bf16* base = zx + (size_t)row * kDInProj + kDInner + c0;
    bf16x8 z8 = {};
    bf16x8 r3 = *(const bf16x8*)(base);
    bf16x8 r2 = (s >= 1) ? *(const bf16x8*)(base - kDInProj) : z8;
    bf16x8 r1 = (s >= 2) ? *(const bf16x8*)(base - 2 * kDInProj) : z8;
    bf16x8 r0 = (s >= 3) ? *(const bf16x8*)(base - 3 * kDInProj) : z8;
    bf16x8 o;
#pragma unroll
    for (int e = 0; e < 8; ++e) {
      float4 w = ((const float4*)cw)[c0 + e];
      float a = cb[c0 + e] + w.x * (float)r0[e] + w.y * (float)r1[e] +
                w.z * (float)r2[e] + w.w * (float)r3[e];
      o[e] = (bf16)siluf(a);
    }
    *(bf16x8*)(xbc + (size_t)row * kConvDim + c0) = o;
  } else { // dt path: kRows*4 threads
    const int g2 = gid - kRows * 272;
    const int row = g2 >> 2, grp = g2 & 3;
    bf16x8 r8 = *(const bf16x8*)(zx + (size_t)row * kDInProj + (kDInner + kConvDim) + grp * 8);
#pragma unroll
    for (int e = 0; e < 8; ++e) {
      int hh = grp * 8 + e;
      float raw = (float)r8[e] + dt_bias[hh];
      float dtv = (raw > 20.f) ? raw : log1pf(expf(raw));
      dt[row * kHeads + hh] = dtv;
      ldA[row * kHeads + hh] = dtv * -expf(A_log[hh]);
    }
  }
}

// ================= chunked SSD scan =================
// Pass A (slimmed): cum-prefix + chunk state S_c = X^T·(wB) ONLY.
// (y_intra moved to pass C -> saves 67 MB of yb write+read traffic.)
__global__ __launch_bounds__(256) void k_chunkA(
    const bf16* __restrict__ xbc, const float* __restrict__ dtb,
    const float* __restrict__ ldab, float* __restrict__ cumbuf,
    float* __restrict__ Tc, bf16* __restrict__ Sbuf) {
  const int c = blockIdx.x, h = blockIdx.y, b = blockIdx.z;
  const int tid = threadIdx.x;
  const int w = tid >> 6, lane = tid & 63, lr = lane & 15, kb = lane >> 4;
  const int rr = kb * 4;
  const int t0 = c * kChunk;
  __shared__ bf16 Bl[64 * 72], XT[64 * 72], WBT[64 * 72];
  __shared__ float w_s[64];

  { // stage B (row-major) and X^T
    int s = tid >> 2, q = tid & 3;
    const bf16* rowp = xbc + ((size_t)b * kSeq + t0 + s) * kConvDim;
    bf16x8 x0 = *(const bf16x8*)(rowp + h * 64 + q * 16);
    bf16x8 x1 = *(const bf16x8*)(rowp + h * 64 + q * 16 + 8);
    bf16x8 b0 = *(const bf16x8*)(rowp + kDInner + q * 16);
    bf16x8 b1 = *(const bf16x8*)(rowp + kDInner + q * 16 + 8);
    *(bf16x8*)(Bl + s * 72 + q * 16) = b0;
    *(bf16x8*)(Bl + s * 72 + q * 16 + 8) = b1;
#pragma unroll
    for (int e = 0; e < 8; ++e) XT[(q * 16 + e) * 72 + s] = x0[e];
#pragma unroll
    for (int e = 0; e < 8; ++e) XT[(q * 16 + 8 + e) * 72 + s] = x1[e];
  }
  if (tid < 64) { // wave 0: inclusive prefix of ldA
    size_t di = ((size_t)b * kSeq + t0 + tid) * kHeads + h;
    float v = ldab[di];
    float dtv = dtb[di];
#pragma unroll
    for (int o = 1; o < 64; o <<= 1) {
      float u = __shfl_up(v, o);
      if (lane >= o) v += u;
    }
    float tot = __shfl(v, 63);
    w_s[tid] = expf(tot - v) * dtv;
    cumbuf[(((size_t)b * kHeads + h) * kNChunk + c) * 64 + tid] = v;
    if (tid == 63) Tc[(b * kHeads + h) * kNChunk + c] = expf(v);
  }
  __syncthreads();

  // WBT[n][s] = B[s][n] * w[s]
#pragma unroll
  for (int i = 0; i < 16; ++i) {
    int e = i * 256 + tid;
    int n = e >> 6, s = e & 63;
    WBT[n * 72 + s] = (bf16)((float)Bl[s * 72 + n] * w_s[s]);
  }
  __syncthreads();

  // S[p,n] = sum_s x[s,p] w[s] B[s,n]
  f32x4 s4[4];
#pragma unroll
  for (int nt = 0; nt < 4; ++nt) s4[nt] = (f32x4){0.f, 0.f, 0.f, 0.f};
#pragma unroll
  for (int kk = 0; kk < 2; ++kk) {
    bf16x8 a = *(const bf16x8*)(XT + (w * 16 + lr) * 72 + kk * 32 + kb * 8);
#pragma unroll
    for (int nt = 0; nt < 4; ++nt) {
      bf16x8 bb = *(const bf16x8*)(WBT + (nt * 16 + lr) * 72 + kk * 32 + kb * 8);
      s4[nt] = __builtin_amdgcn_mfma_f32_16x16x32_bf16(a, bb, s4[nt], 0, 0, 0);
    }
  }
  // Bl dead -> transpose scratch; vectorized full-line stores
#pragma unroll
  for (int nt = 0; nt < 4; ++nt)
#pragma unroll
    for (int j = 0; j < 4; ++j)
      Bl[(w * 16 + rr + j) * 72 + nt * 16 + lr] = (bf16)s4[nt][j];
  __syncthreads();
  {
    int row = tid >> 2, cg = tid & 3;
    const size_t sbase = (((size_t)b * kHeads + h) * kNChunk + c) * 4096;
    bf16x8 u0 = *(const bf16x8*)(Bl + row * 72 + cg * 16);
    bf16x8 u1 = *(const bf16x8*)(Bl + row * 72 + cg * 16 + 8);
    bf16* sdst = Sbuf + sbase + row * 64 + cg * 16;
    *(bf16x8*)sdst = u0;
    *(bf16x8*)(sdst + 8) = u1;
  }
}

// Pass B: serial scan over 32 chunks, in-place (bf16 states, fp32 accum)
__global__ __launch_bounds__(256) void k_chunkB(bf16* __restrict__ S,
                                                const float* __restrict__ Tc) {
  const int gid = blockIdx.x * 256 + threadIdx.x;
  const int bh = gid >> 10;
  const int pn = (gid & 1023) << 2;
  bf16* base = S + (size_t)bh * kNChunk * 4096 + pn;
  const float* tc = Tc + bh * kNChunk;
  float4 hh = {0.f, 0.f, 0.f, 0.f};
  bf16x4 s = *(const bf16x4*)(base);
  for (int c = 0; c < kNChunk; ++c) {
    bf16x4 sn = {};
    if (c + 1 < kNChunk) sn = *(const bf16x4*)(base + (size_t)(c + 1) * 4096);
    float t = tc[c];
    bf16x4 ho;
    ho[0] = (bf16)hh.x; ho[1] = (bf16)hh.y; ho[2] = (bf16)hh.z; ho[3] = (bf16)hh.w;
    *(bf16x4*)(base + (size_t)c * 4096) = ho;
    hh.x = t * hh.x + (float)s[0];
    hh.y = t * hh.y + (float)s[1];
    hh.z = t * hh.z + (float)s[2];
    hh.w = t * hh.w + (float)s[3];
    s = sn;
  }
}

// Pass C (full y): G=C·B^T, M=G*decay*dt masked, y_intra=M·X, plus
// ecum*(C·h0) + D*x, gate with silu(z) -> single pure store of g into yb.
__global__ __launch_bounds__(256) void k_chunkC(
    const bf16* __restrict__ xbc, const bf16* __restrict__ zx,
    const float* __restrict__ dtb, const float* __restrict__ cumbuf,
    const bf16* __restrict__ hs, const float* __restrict__ Dp,
    bf16* __restrict__ yb) {
  const int c = blockIdx.x, h = blockIdx.y, b = blockIdx.z;
  const int tid = threadIdx.x;
  const int w = tid >> 6, lane = tid & 63, lr = lane & 15, kb = lane >> 4;
  const int rr = kb * 4;
  const int t0 = c * kChunk;
  __shared__ bf16 Bl[64 * 72], Cl[64 * 72], XT[64 * 72], Ml[64 * 72];
  __shared__ float cum_s[64], dt_s[64], ecum[64];
  __shared__ float scrf[64 * 68];

  { // stage B, C (row-major) and X^T
    int s = tid >> 2, q = tid & 3;
    const bf16* rowp = xbc + ((size_t)b * kSeq + t0 + s) * kConvDim;
    bf16x8 x0 = *(const bf16x8*)(rowp + h * 64 + q * 16);
    bf16x8 x1 = *(const bf16x8*)(rowp + h * 64 + q * 16 + 8);
    bf16x8 b0 = *(const bf16x8*)(rowp + kDInner + q * 16);
    bf16x8 b1 = *(const bf16x8*)(rowp + kDInner + q * 16 + 8);
    bf16x8 c0 = *(const bf16x8*)(rowp + kDInner + 64 + q * 16);
    bf16x8 c1 = *(const bf16x8*)(rowp + kDInner + 64 + q * 16 + 8);
    *(bf16x8*)(Bl + s * 72 + q * 16) = b0;
    *(bf16x8*)(Bl + s * 72 + q * 16 + 8) = b1;
    *(bf16x8*)(Cl + s * 72 + q * 16) = c0;
    *(bf16x8*)(Cl + s * 72 + q * 16 + 8) = c1;
#pragma unroll
    for (int e = 0; e < 8; ++e) XT[(q * 16 + e) * 72 + s] = x0[e];
#pragma unroll
    for (int e = 0; e < 8; ++e) XT[(q * 16 + 8 + e) * 72 + s] = x1[e];
  }
  if (tid < 64) {
    size_t di = ((size_t)b * kSeq + t0 + tid) * kHeads + h;
    float cv = cumbuf[(((size_t)b * kHeads + h) * kNChunk + c) * 64 + tid];
    cum_s[tid] = cv;
    ecum[tid] = expf(cv);
    dt_s[tid] = dtb[di];
  }
  __syncthreads();

  // G[t,s] = sum_n C[t,n] B[s,n]
  f32x4 g[4];
#pragma unroll
  for (int nt = 0; nt < 4; ++nt) g[nt] = (f32x4){0.f, 0.f, 0.f, 0.f};
#pragma unroll
  for (int kk = 0; kk < 2; ++kk) {
    bf16x8 a = *(const bf16x8*)(Cl + (w * 16 + lr) * 72 + kk * 32 + kb * 8);
#pragma unroll
    for (int nt = 0; nt < 4; ++nt) {
      bf16x8 bb = *(const bf16x8*)(Bl + (nt * 16 + lr) * 72 + kk * 32 + kb * 8);
      g[nt] = __builtin_amdgcn_mfma_f32_16x16x32_bf16(a, bb, g[nt], 0, 0, 0);
    }
  }
#pragma unroll
  for (int nt = 0; nt < 4; ++nt)
#pragma unroll
    for (int j = 0; j < 4; ++j) {
      int tt = w * 16 + rr + j, ss = nt * 16 + lr;
      float m = (ss <= tt) ? g[nt][j] * expf(cum_s[tt] - cum_s[ss]) * dt_s[ss] : 0.f;
      Ml[tt * 72 + ss] = (bf16)m;
    }
  __syncthreads();

  // y_intra[t,p] = sum_s M[t,s] x[s,p]
  f32x4 y4[4];
#pragma unroll
  for (int pt = 0; pt < 4; ++pt) y4[pt] = (f32x4){0.f, 0.f, 0.f, 0.f};
#pragma unroll
  for (int kk = 0; kk < 2; ++kk) {
    bf16x8 a = *(const bf16x8*)(Ml + (w * 16 + lr) * 72 + kk * 32 + kb * 8);
#pragma unroll
    for (int pt = 0; pt < 4; ++pt) {
      bf16x8 bb = *(const bf16x8*)(XT + (pt * 16 + lr) * 72 + kk * 32 + kb * 8);
      y4[pt] = __builtin_amdgcn_mfma_f32_16x16x32_bf16(a, bb, y4[pt], 0, 0, 0);
    }
  }
  // y_inter fragments: acc2[t,p] = sum_n C[t,n] h0[p,n]
  const bf16* hbase = hs + (((size_t)b * kHeads + h) * kNChunk + c) * 4096;
  f32x4 acc2[4];
#pragma unroll
  for (int pt = 0; pt < 4; ++pt) acc2[pt] = (f32x4){0.f, 0.f, 0.f, 0.f};
#pragma unroll
  for (int kk = 0; kk < 2; ++kk) {
    bf16x8 a = *(const bf16x8*)(Cl + (w * 16 + lr) * 72 + kk * 32 + kb * 8);
#pragma unroll
    for (int pt = 0; pt < 4; ++pt) {
      bf16x8 bb = *(const bf16x8*)(hbase + (pt * 16 + lr) * 64 + kk * 32 + kb * 8);
      acc2[pt] = __builtin_amdgcn_mfma_f32_16x16x32_bf16(a, bb, acc2[pt], 0, 0, 0);
    }
  }
  // combine in f32: y_intra + ecum * y_inter -> scrf
#pragma unroll
  for (int pt = 0; pt < 4; ++pt)
#pragma unroll
    for (int j = 0; j < 4; ++j) {
      int tt = w * 16 + rr + j;
      scrf[tt * 68 + pt * 16 + lr] = y4[pt][j] + ecum[tt] * acc2[pt][j];
    }
  __syncthreads();
  { // epilogue: + D*x, gate with silu(z), single vectorized store
    const float Dh = Dp[h];
    int row = tid >> 2, cg = tid & 3;
    size_t ri = (size_t)b * kSeq + t0 + row;
    const float* sp = scrf + row * 68 + cg * 16;
    bf16* yp = yb + ri * kDInner + h * 64 + cg * 16;
    const bf16* xp = xbc + ri * kConvDim + h * 64 + cg * 16;
    const bf16* zp = zx + ri * kDInProj + h * 64 + cg * 16;
#pragma unroll
    for (int half = 0; half < 2; ++half) {
      bf16x8 xv = *(const bf16x8*)(xp + half * 8);
      bf16x8 zv = *(const bf16x8*)(zp + half * 8);
      bf16x8 o;
#pragma unroll
      for (int e = 0; e < 8; ++e) {
        float yfull = sp[half * 8 + e] + Dh * (float)xv[e];
        o[e] = (bf16)(yfull * siluf((float)zv[e]));
      }
      *(bf16x8*)(yp + half * 8) = o;
    }
  }
}

extern "C" void kernel_launch(void* const* d_in, const int* in_sizes, int n_in,
                              void* d_out, int out_size, void* d_ws, size_t ws_size,
                              hipStream_t stream) {
  const float* x = (const float*)d_in[0];
  const float* norm_w = (const float*)d_in[1];
  const float* r_w1 = (const float*)d_in[2];
  const float* r_b1 = (const float*)d_in[3];
  const float* r_w2 = (const float*)d_in[4];
  const float* r_b2 = (const float*)d_in[5];
  const float* in_proj_w = (const float*)d_in[6];
  const float* conv_w = (const float*)d_in[7];
  const float* conv_b = (const float*)d_in[8];
  const float* dt_bias = (const float*)d_in[9];
  const float* A_log = (const float*)d_in[10];
  const float* D_param = (const float*)d_in[11];
  const float* gnorm_w = (const float*)d_in[12];
  const float* out_proj_w = (const float*)d_in[13];
  float* out = (float*)d_out;
  char* ws = (char*)d_ws;

  // workspace layout (~207 MB)
  bf16* xnb     = (bf16*)(ws + 0);           // 16,777,216
  bf16* w1b     = (bf16*)(ws + 16777216);    //  8,912,896
  bf16* zx      = (bf16*)(ws + 25690112);    // 69,730,304
  bf16* xbc     = (bf16*)(ws + 95420416);    // 35,651,584
  float* dtb    = (float*)(ws + 131072000);  //  1,048,576
  float* ldab   = (float*)(ws + 132120576);  //  1,048,576
  float* cumbuf = (float*)(ws + 133169152);  //  1,048,576
  float* Tcb    = (float*)(ws + 134217728);  //     16,384
  bf16* yb      = (bf16*)(ws + 134234112);   // 33,554,432 (g written once)
  bf16* Sbuf    = (bf16*)(ws + 167788544);   // 33,554,432
  bf16* w2b     = (bf16*)(ws + 201342976);   //  4,194,304
  float* part   = (float*)(ws + 205537280);  //  1,048,576
  float* meanb  = (float*)(ws + 206585856);  //     16,384
  float* pfm    = (float*)(ws + 206602240);  //        128
  float* rsb    = (float*)(ws + 206602368);  //     32,768

  k_pre<<<kRows + kW1Blocks + kW2Blocks, 256, 0, stream>>>(
      x, norm_w, xnb, rsb, in_proj_w, w1b, out_proj_w, gnorm_w, w2b);
  k_pool1<<<dim3(64, 4), 128, 0, stream>>>(xnb, part);
  k_pool2<<<16, 256, 0, stream>>>(part, meanb);
  k_router<<<1, 128, 0, stream>>>(meanb, r_w1, r_b1, r_w2, r_b2, pfm);
  // zxbcdt = x_norm @ in_proj_w.T  [8192 x 4256] ; BM=128,BN=256: 64*17=1088
  k_gemm_in<<<(kRows / 128) * (kNPad1 / 256), 512, 0, stream>>>(
      xnb, w1b, zx, kDModel, kDInProj, kDInProj, kNPad1 / 256);
  k_convdt<<<(kRows * 272 + kRows * 4) / 256, 256, 0, stream>>>(
      zx, conv_w, conv_b, xbc, dt_bias, A_log, dtb, ldab);
  k_chunkA<<<dim3(kNChunk, kHeads, kBatch), 256, 0, stream>>>(
      xbc, dtb, ldab, cumbuf, Tcb, Sbuf);
  k_chunkB<<<512, 256, 0, stream>>>(Sbuf, Tcb);
  k_chunkC<<<dim3(kNChunk, kHeads, kBatch), 256, 0, stream>>>(
      xbc, zx, dtb, cumbuf, Sbuf, D_param, yb);
  // out = x + pf*x_norm + pm*rs2*(g @ (out_proj_w*gw).T); rs2 fused in-kernel
  k_gemm_out<<<(kRows / 64) * (kDModel / 128), 256, 0, stream>>>(
      yb, w2b, x, rsb, norm_w, pfm, out,
      kDInner, kDModel, kDModel, kDModel / 128);
}